// Round 4
// baseline (147.542 us; speedup 1.0000x reference)
//
#include <hip/hip_runtime.h>
#include <stdint.h>

// MLA attention, MI355X round 4.
// Stage 1: kv = compressed_kv @ w_up^T  (bf16 MFMA, m97-style 128x128 tile)
// Stage 2: causal flash attention, bf16 MFMA. Round-4: async dbuf K staging via
//          global_load_lds + XOR swizzle, V reg-prefetch (16 VGPR), 1024 blocks
//          (64-row q-tiles) for backfill load balancing.

#define Bz 4
#define Sz 1024
#define Hz 16
#define RANKz 512
#define SCALEf 0.07216878364870323f

typedef __attribute__((ext_vector_type(8))) short bf16x8;
typedef __attribute__((ext_vector_type(4))) float f32x4;

__device__ __forceinline__ unsigned short f2b(float f) {
  union { float f; uint32_t u; } x; x.f = f;
  return (unsigned short)((x.u + 0x7fffu + ((x.u >> 16) & 1u)) >> 16);
}

// ---------------------------------------------------------------- cvt fp32->bf16
__global__ void cvt_bf16_kernel(const float* __restrict__ a, unsigned short* __restrict__ ao,
                                const float* __restrict__ b, unsigned short* __restrict__ bo,
                                const float* __restrict__ c, unsigned short* __restrict__ co,
                                int na, int nb) {
  int idx = blockIdx.x * blockDim.x + threadIdx.x;
  const float* s; unsigned short* d; int i;
  if (idx < na)            { s = a; d = ao; i = idx; }
  else if (idx < na + nb)  { s = b; d = bo; i = idx - na; }
  else                     { s = c; d = co; i = idx - na - nb; }
  float4 v = ((const float4*)s)[i];
  ushort4 o = make_ushort4(f2b(v.x), f2b(v.y), f2b(v.z), f2b(v.w));
  ((ushort4*)d)[i] = o;
}

// ---------------------------------------------------------------- stage 1 GEMM
__global__ __launch_bounds__(256)
void gemm_kv_bf16(const unsigned short* __restrict__ A,
                  const unsigned short* __restrict__ Bm,
                  unsigned short* __restrict__ C) {
  __shared__ unsigned short As[128 * 32];
  __shared__ unsigned short Bs[128 * 32];
  const int tid = threadIdx.x;
  const int w = tid >> 6, lane = tid & 63;
  const int wr = w >> 1, wc = w & 1;
  const int row0 = blockIdx.x * 128, col0 = blockIdx.y * 128;
  f32x4 acc[4][4];
#pragma unroll
  for (int m = 0; m < 4; ++m)
#pragma unroll
    for (int n = 0; n < 4; ++n) acc[m][n] = (f32x4){0.f, 0.f, 0.f, 0.f};

  const int rstage = (lane >> 2);
  const int cstage = (lane & 3) * 8;

  for (int kt = 0; kt < RANKz / 32; ++kt) {
    const int k0 = kt * 32;
#pragma unroll
    for (int i = 0; i < 2; ++i) {
      const int chunk = i * 4 + w;
      const int r = chunk * 16 + rstage;
      const unsigned short* ga = A  + (size_t)(row0 + r) * RANKz + k0 + cstage;
      const unsigned short* gb = Bm + (size_t)(col0 + r) * RANKz + k0 + cstage;
      __builtin_amdgcn_global_load_lds((const __attribute__((address_space(1))) void*)ga,
                                       (__attribute__((address_space(3))) void*)&As[chunk * 512], 16, 0, 0);
      __builtin_amdgcn_global_load_lds((const __attribute__((address_space(1))) void*)gb,
                                       (__attribute__((address_space(3))) void*)&Bs[chunk * 512], 16, 0, 0);
    }
    __syncthreads();
    const int klo = (lane >> 4) * 8;
    bf16x8 af[4], bfr[4];
#pragma unroll
    for (int m = 0; m < 4; ++m)
      af[m] = *(const bf16x8*)&As[(wr * 64 + m * 16 + (lane & 15)) * 32 + klo];
#pragma unroll
    for (int n = 0; n < 4; ++n)
      bfr[n] = *(const bf16x8*)&Bs[(wc * 64 + n * 16 + (lane & 15)) * 32 + klo];
#pragma unroll
    for (int m = 0; m < 4; ++m)
#pragma unroll
      for (int n = 0; n < 4; ++n)
        acc[m][n] = __builtin_amdgcn_mfma_f32_16x16x32_bf16(af[m], bfr[n], acc[m][n], 0, 0, 0);
    __syncthreads();
  }
  const int cb = col0 + wc * 64 + (lane & 15);
  const int rb = row0 + wr * 64 + (lane >> 4) * 4;
#pragma unroll
  for (int m = 0; m < 4; ++m)
#pragma unroll
    for (int n = 0; n < 4; ++n)
#pragma unroll
      for (int j = 0; j < 4; ++j)
        C[(size_t)(rb + m * 16 + j) * 4096 + (cb + n * 16)] = f2b(acc[m][n][j]);
}

// ---------------------------------------------------------------- stage 2: MFMA attention
// grid (16, 64): s = 15-bx (heavy first), bh = by. 256 thr = 4 waves x 16 q-rows.
// KV tile 64. Kn/Kr: gll double-buffer + XOR swizzle (chunk16 ^= row&7).
// Vt: single-buffer swizzled packed-pair; V(t+1) reg-prefetched (16 VGPR).
__global__ __launch_bounds__(256, 2)
void mla_attn_mfma(const float* __restrict__ q,
                   const unsigned short* __restrict__ kvb,   // [T][16*256] bf16
                   const unsigned short* __restrict__ ropeb, // [T][64] bf16
                   float* __restrict__ out) {                // [T][16][128] fp32
  __shared__ unsigned short Kn[2][64 * 128];   // 32 KB, swizzled
  __shared__ unsigned short Kr[2][64 * 64];    // 16 KB, swizzled
  __shared__ unsigned short Vt[128 * 64];      // 16 KB, transposed+swizzled (k-pairs packed)
  __shared__ unsigned short Ps[4][16][72];     // 9.2 KB per-wave P round-trip

  const int tid = threadIdx.x;
  const int w = tid >> 6, lane = tid & 63;
  const int lr = lane & 15, lg = lane >> 4;
  const int s = 15 - (int)blockIdx.x;
  const int bh = blockIdx.y;
  const int bat = bh >> 4, h = bh & 15;
  const int qbase = s * 64;
  const int row0 = qbase + w * 16;
  const int tok0 = bat * Sz;

  // ---- Q fragments, prescaled, bf16, registers (one 16-row m-tile per wave)
  bf16x8 qf[6];
  {
    const int qrow = row0 + lr;
    const float* qp = q + ((size_t)(tok0 + qrow) * Hz + h) * 192 + lg * 8;
#pragma unroll
    for (int ks = 0; ks < 6; ++ks) {
      float4 a = *(const float4*)(qp + ks * 32);
      float4 b = *(const float4*)(qp + ks * 32 + 4);
      union { bf16x8 v; unsigned short u[8]; } t;
      t.u[0] = f2b(a.x * SCALEf); t.u[1] = f2b(a.y * SCALEf);
      t.u[2] = f2b(a.z * SCALEf); t.u[3] = f2b(a.w * SCALEf);
      t.u[4] = f2b(b.x * SCALEf); t.u[5] = f2b(b.y * SCALEf);
      t.u[6] = f2b(b.z * SCALEf); t.u[7] = f2b(b.w * SCALEf);
      qf[ks] = t.v;
    }
  }

  f32x4 acc[8];
#pragma unroll
  for (int n = 0; n < 8; ++n) acc[n] = (f32x4){0.f, 0.f, 0.f, 0.f};
  float m_run[4], l_run[4];
#pragma unroll
  for (int j = 0; j < 4; ++j) { m_run[j] = -1e30f; l_run[j] = 0.f; }

  const int ntiles = s + 1;
  const int vkp = tid & 31, vdc = tid >> 5;      // V-prefetch: k-pair, d-chunk(16)
  uint4 v0a, v0b, v1a, v1b;                      // V prefetch regs (16 VGPR)

  // ---- issue gll K(0) + load V(0)
  {
#pragma unroll
    for (int i = 0; i < 4; ++i) {                // Kn: 16 chunks of 1 KB
      const int c = w * 4 + i;
      const int row = c * 4 + (lane >> 4);
      const int lc16 = (lane & 15) ^ (row & 7);
      const unsigned short* src = kvb + ((size_t)(tok0 + row) * Hz + h) * 256 + lc16 * 8;
      __builtin_amdgcn_global_load_lds((const __attribute__((address_space(1))) void*)src,
                                       (__attribute__((address_space(3))) void*)&Kn[0][c * 512], 16, 0, 0);
    }
#pragma unroll
    for (int i = 0; i < 2; ++i) {                // Kr: 8 chunks of 1 KB
      const int c = w * 2 + i;
      const int row = c * 8 + (lane >> 3);
      const int lc8 = (lane & 7) ^ (row & 7);
      const unsigned short* src = ropeb + (size_t)(tok0 + row) * 64 + lc8 * 8;
      __builtin_amdgcn_global_load_lds((const __attribute__((address_space(1))) void*)src,
                                       (__attribute__((address_space(3))) void*)&Kr[0][c * 512], 16, 0, 0);
    }
    const unsigned short* vp = kvb + ((size_t)tok0 * Hz + h) * 256 + 128;
    v0a = *(const uint4*)(vp + (size_t)(vkp * 2) * 4096 + vdc * 16);
    v0b = *(const uint4*)(vp + (size_t)(vkp * 2) * 4096 + vdc * 16 + 8);
    v1a = *(const uint4*)(vp + (size_t)(vkp * 2 + 1) * 4096 + vdc * 16);
    v1b = *(const uint4*)(vp + (size_t)(vkp * 2 + 1) * 4096 + vdc * 16 + 8);
  }
  __syncthreads();    // drains gll(0); V regs valid (waitcnt by compiler)

  // ---- write V(0) to Vt (packed pairs, swizzled)
  {
    const uint32_t r0[4] = {v0a.x, v0a.y, v0a.z, v0a.w};
    const uint32_t r1[4] = {v1a.x, v1a.y, v1a.z, v1a.w};
    const uint32_t r2[4] = {v0b.x, v0b.y, v0b.z, v0b.w};
    const uint32_t r3[4] = {v1b.x, v1b.y, v1b.z, v1b.w};
    char* vtb = (char*)Vt;
    const int inchunk = (4 * vkp) & 15, c16 = vkp >> 2;
#pragma unroll
    for (int wd = 0; wd < 4; ++wd) {
#pragma unroll
      for (int half = 0; half < 2; ++half) {
        { const int d = vdc * 16 + wd * 2 + half;
          const uint32_t val = half ? ((r0[wd] >> 16) | (r1[wd] & 0xffff0000u))
                                    : ((r0[wd] & 0xffffu) | (r1[wd] << 16));
          *(uint32_t*)(vtb + d * 128 + 16 * (c16 ^ (d & 7)) + inchunk) = val; }
        { const int d = vdc * 16 + 8 + wd * 2 + half;
          const uint32_t val = half ? ((r2[wd] >> 16) | (r3[wd] & 0xffff0000u))
                                    : ((r2[wd] & 0xffffu) | (r3[wd] << 16));
          *(uint32_t*)(vtb + d * 128 + 16 * (c16 ^ (d & 7)) + inchunk) = val; }
      }
    }
  }
  __syncthreads();    // publish Vt(0)

  for (int t = 0; t < ntiles; ++t) {
    const int cur = t & 1;
    const int ks0 = t * 64;
    const bool havenext = (t + 1 < ntiles);

    // ---- issue gll K(t+1) into buf cur^1; load V(t+1) regs
    if (havenext) {
      const int tokn = tok0 + (t + 1) * 64;
#pragma unroll
      for (int i = 0; i < 4; ++i) {
        const int c = w * 4 + i;
        const int row = c * 4 + (lane >> 4);
        const int lc16 = (lane & 15) ^ (row & 7);
        const unsigned short* src = kvb + ((size_t)(tokn + row) * Hz + h) * 256 + lc16 * 8;
        __builtin_amdgcn_global_load_lds((const __attribute__((address_space(1))) void*)src,
                                         (__attribute__((address_space(3))) void*)&Kn[cur ^ 1][c * 512], 16, 0, 0);
      }
#pragma unroll
      for (int i = 0; i < 2; ++i) {
        const int c = w * 2 + i;
        const int row = c * 8 + (lane >> 3);
        const int lc8 = (lane & 7) ^ (row & 7);
        const unsigned short* src = ropeb + (size_t)(tokn + row) * 64 + lc8 * 8;
        __builtin_amdgcn_global_load_lds((const __attribute__((address_space(1))) void*)src,
                                         (__attribute__((address_space(3))) void*)&Kr[cur ^ 1][c * 512], 16, 0, 0);
      }
      const unsigned short* vp = kvb + ((size_t)tokn * Hz + h) * 256 + 128;
      v0a = *(const uint4*)(vp + (size_t)(vkp * 2) * 4096 + vdc * 16);
      v0b = *(const uint4*)(vp + (size_t)(vkp * 2) * 4096 + vdc * 16 + 8);
      v1a = *(const uint4*)(vp + (size_t)(vkp * 2 + 1) * 4096 + vdc * 16);
      v1b = *(const uint4*)(vp + (size_t)(vkp * 2 + 1) * 4096 + vdc * 16 + 8);
    }

    // ---- QK^T: S[16 q][64 k] over d=192 (swizzled reads, 2-way banks)
    const unsigned short* KnC = &Kn[cur][0];
    const unsigned short* KrC = &Kr[cur][0];
    f32x4 sfr[4];
#pragma unroll
    for (int n = 0; n < 4; ++n) sfr[n] = (f32x4){0.f, 0.f, 0.f, 0.f};
#pragma unroll
    for (int ks = 0; ks < 4; ++ks)
#pragma unroll
      for (int n = 0; n < 4; ++n) {
        const int row = n * 16 + lr;
        bf16x8 bk = *(const bf16x8*)&KnC[row * 128 + 8 * ((ks * 4 + lg) ^ (lr & 7))];
        sfr[n] = __builtin_amdgcn_mfma_f32_16x16x32_bf16(qf[ks], bk, sfr[n], 0, 0, 0);
      }
#pragma unroll
    for (int ks = 4; ks < 6; ++ks)
#pragma unroll
      for (int n = 0; n < 4; ++n) {
        const int row = n * 16 + lr;
        bf16x8 bk = *(const bf16x8*)&KrC[row * 64 + 8 * (((ks - 4) * 4 + lg) ^ (lr & 7))];
        sfr[n] = __builtin_amdgcn_mfma_f32_16x16x32_bf16(qf[ks], bk, sfr[n], 0, 0, 0);
      }

    // ---- causal mask (diagonal tile only: t == s)
    float sv[4][4];
    const bool edge = (ks0 + 63 > row0);
#pragma unroll
    for (int n = 0; n < 4; ++n)
#pragma unroll
      for (int j = 0; j < 4; ++j) {
        float x = sfr[n][j];
        if (edge && (ks0 + n * 16 + lr > row0 + lg * 4 + j)) x = -1e30f;
        sv[n][j] = x;
      }

    // ---- online softmax (rows in 16-lane groups)
    float mxj[4];
#pragma unroll
    for (int j = 0; j < 4; ++j)
      mxj[j] = fmaxf(fmaxf(sv[0][j], sv[1][j]), fmaxf(sv[2][j], sv[3][j]));
#pragma unroll
    for (int off = 1; off < 16; off <<= 1)
#pragma unroll
      for (int j = 0; j < 4; ++j) mxj[j] = fmaxf(mxj[j], __shfl_xor(mxj[j], off));

    float nm[4], cr[4];
#pragma unroll
    for (int j = 0; j < 4; ++j) {
      nm[j] = fmaxf(m_run[j], mxj[j]);
      cr[j] = __expf(m_run[j] - nm[j]);
      m_run[j] = nm[j];
    }
    float p[4][4], ts[4];
#pragma unroll
    for (int n = 0; n < 4; ++n)
#pragma unroll
      for (int j = 0; j < 4; ++j) p[n][j] = __expf(sv[n][j] - nm[j]);
#pragma unroll
    for (int j = 0; j < 4; ++j) ts[j] = (p[0][j] + p[1][j]) + (p[2][j] + p[3][j]);
#pragma unroll
    for (int off = 1; off < 16; off <<= 1)
#pragma unroll
      for (int j = 0; j < 4; ++j) ts[j] += __shfl_xor(ts[j], off);
#pragma unroll
    for (int j = 0; j < 4; ++j) l_run[j] = l_run[j] * cr[j] + ts[j];
#pragma unroll
    for (int n = 0; n < 8; ++n)
#pragma unroll
      for (int j = 0; j < 4; ++j) acc[n][j] *= cr[j];

    // ---- P -> per-wave LDS (C-layout -> A-layout), same-wave ordering safe
#pragma unroll
    for (int n = 0; n < 4; ++n)
#pragma unroll
      for (int j = 0; j < 4; ++j)
        Ps[w][lg * 4 + j][n * 16 + lr] = f2b(p[n][j]);

    // ---- PV: O[16 q][128 d] += P[16][64] * V[64][128] (Vt swizzled reads)
#pragma unroll
    for (int kstep = 0; kstep < 2; ++kstep) {
      bf16x8 pa = *(const bf16x8*)&Ps[w][lr][kstep * 32 + lg * 8];
#pragma unroll
      for (int n = 0; n < 8; ++n) {
        const int row = n * 16 + lr;
        bf16x8 bv = *(const bf16x8*)&Vt[row * 64 + 8 * ((kstep * 4 + lg) ^ (lr & 7))];
        acc[n] = __builtin_amdgcn_mfma_f32_16x16x32_bf16(pa, bv, acc[n], 0, 0, 0);
      }
    }

    __syncthreads();   // A: everyone done with Vt(t), Kn/Kr[cur]; gll(t+1) drained

    if (havenext) {    // write V(t+1) regs -> Vt, publish
      const uint32_t r0[4] = {v0a.x, v0a.y, v0a.z, v0a.w};
      const uint32_t r1[4] = {v1a.x, v1a.y, v1a.z, v1a.w};
      const uint32_t r2[4] = {v0b.x, v0b.y, v0b.z, v0b.w};
      const uint32_t r3[4] = {v1b.x, v1b.y, v1b.z, v1b.w};
      char* vtb = (char*)Vt;
      const int inchunk = (4 * vkp) & 15, c16 = vkp >> 2;
#pragma unroll
      for (int wd = 0; wd < 4; ++wd) {
#pragma unroll
        for (int half = 0; half < 2; ++half) {
          { const int d = vdc * 16 + wd * 2 + half;
            const uint32_t val = half ? ((r0[wd] >> 16) | (r1[wd] & 0xffff0000u))
                                      : ((r0[wd] & 0xffffu) | (r1[wd] << 16));
            *(uint32_t*)(vtb + d * 128 + 16 * (c16 ^ (d & 7)) + inchunk) = val; }
          { const int d = vdc * 16 + 8 + wd * 2 + half;
            const uint32_t val = half ? ((r2[wd] >> 16) | (r3[wd] & 0xffff0000u))
                                      : ((r2[wd] & 0xffffu) | (r3[wd] << 16));
            *(uint32_t*)(vtb + d * 128 + 16 * (c16 ^ (d & 7)) + inchunk) = val; }
        }
      }
      __syncthreads(); // B: Vt(t+1) published
    }
  }

  // ---- epilogue
  {
    float inv[4];
#pragma unroll
    for (int j = 0; j < 4; ++j) inv[j] = 1.0f / l_run[j];
    const int qrow = row0 + lg * 4;
#pragma unroll
    for (int n = 0; n < 8; ++n)
#pragma unroll
      for (int j = 0; j < 4; ++j)
        out[((size_t)(tok0 + qrow + j) * Hz + h) * 128 + n * 16 + lr] = acc[n][j] * inv[j];
  }
}

// ---------------------------------------------------------------- launch
extern "C" void kernel_launch(void* const* d_in, const int* in_sizes, int n_in,
                              void* d_out, int out_size, void* d_ws, size_t ws_size,
                              hipStream_t stream) {
  const float* q    = (const float*)d_in[0];
  const float* ckv  = (const float*)d_in[1];
  const float* rope = (const float*)d_in[2];
  const float* wup  = (const float*)d_in[3];
  float* out = (float*)d_out;

  unsigned short* ckvb = (unsigned short*)d_ws;
  unsigned short* wupb = ckvb + (size_t)4096 * RANKz;
  unsigned short* kvb  = wupb + (size_t)4096 * RANKz;
  unsigned short* ropeb = kvb + (size_t)4096 * 4096;

  const int nvec = 4096 * RANKz / 4;       // 524288 float4 per matrix
  const int nrope = 4096 * 64 / 4;         // 65536 float4
  cvt_bf16_kernel<<<(2 * nvec + nrope) / 256, 256, 0, stream>>>(ckv, ckvb, wup, wupb, rope, ropeb, nvec, nvec);

  dim3 gg(32, 32);
  gemm_kv_bf16<<<gg, 256, 0, stream>>>(ckvb, wupb, kvb);

  dim3 ga(16, 64);
  mla_attn_mfma<<<ga, 256, 0, stream>>>(q, kvb, ropeb, out);
}

// Round 5
// 90.003 us; speedup vs baseline: 1.6393x; 1.6393x over previous
//
#include <hip/hip_runtime.h>
#include <stdint.h>

// MLA attention, MI355X round 5.
// Stage 1: kv = compressed_kv @ w_up^T  (bf16 MFMA, m97-style 128x128 tile)
// Stage 2: causal flash attention, 8-wave swapped-QK^T 32x32x16 structure:
//   - wave = (k-half, q-strip); KV tile 128; independent online-softmax per
//     k-half, merged once at end (LDS).
//   - swapped mfma(K,Q): lane owns q-column -> in-register softmax
//     (31 fmax + 1 shfl_xor(32)); P -> A-frag via v_cvt_pk_bf16_f32 + word swap.
//   - Kn/Kr via global_load_lds, XOR-swizzled double buffers; V reg-prefetch ->
//     packed transposed swizzled Vt.
//   - causal balance: block = q-tile pair (7-p, p) -> 9 tile-computes/block,
//     256 blocks, 1/CU; XCD-chunk swizzle for per-bh KV L2 reuse.

#define Hz 16
#define Sz 1024
#define RANKz 512
#define SCALEf 0.07216878364870323f

typedef unsigned short u16;
typedef __attribute__((ext_vector_type(8))) short bf16x8;
typedef __attribute__((ext_vector_type(4))) float f32x4;
typedef __attribute__((ext_vector_type(16))) float f32x16;

__device__ __forceinline__ u16 f2b(float f) {
  union { float f; uint32_t u; } x; x.f = f;
  return (u16)((x.u + 0x7fffu + ((x.u >> 16) & 1u)) >> 16);
}
__device__ __forceinline__ uint32_t cvtpk(float lo, float hi_) {
  uint32_t r;
  asm("v_cvt_pk_bf16_f32 %0, %1, %2" : "=v"(r) : "v"(lo), "v"(hi_));
  return r;
}

// ---------------------------------------------------------------- cvt fp32->bf16
__global__ void cvt_bf16_kernel(const float* __restrict__ a, u16* __restrict__ ao,
                                const float* __restrict__ b, u16* __restrict__ bo,
                                const float* __restrict__ c, u16* __restrict__ co,
                                int na, int nb) {
  int idx = blockIdx.x * blockDim.x + threadIdx.x;
  const float* s; u16* d; int i;
  if (idx < na)            { s = a; d = ao; i = idx; }
  else if (idx < na + nb)  { s = b; d = bo; i = idx - na; }
  else                     { s = c; d = co; i = idx - na - nb; }
  float4 v = ((const float4*)s)[i];
  ushort4 o = make_ushort4(f2b(v.x), f2b(v.y), f2b(v.z), f2b(v.w));
  ((ushort4*)d)[i] = o;
}

// ---------------------------------------------------------------- stage 1 GEMM
__global__ __launch_bounds__(256)
void gemm_kv_bf16(const u16* __restrict__ A,
                  const u16* __restrict__ Bm,
                  u16* __restrict__ C) {
  __shared__ u16 As[128 * 32];
  __shared__ u16 Bs[128 * 32];
  const int tid = threadIdx.x;
  const int w = tid >> 6, lane = tid & 63;
  const int wr = w >> 1, wc = w & 1;
  const int row0 = blockIdx.x * 128, col0 = blockIdx.y * 128;
  f32x4 acc[4][4];
#pragma unroll
  for (int m = 0; m < 4; ++m)
#pragma unroll
    for (int n = 0; n < 4; ++n) acc[m][n] = (f32x4){0.f, 0.f, 0.f, 0.f};

  const int rstage = (lane >> 2);
  const int cstage = (lane & 3) * 8;

  for (int kt = 0; kt < RANKz / 32; ++kt) {
    const int k0 = kt * 32;
#pragma unroll
    for (int i = 0; i < 2; ++i) {
      const int chunk = i * 4 + w;
      const int r = chunk * 16 + rstage;
      const u16* ga = A  + (size_t)(row0 + r) * RANKz + k0 + cstage;
      const u16* gb = Bm + (size_t)(col0 + r) * RANKz + k0 + cstage;
      __builtin_amdgcn_global_load_lds((const __attribute__((address_space(1))) void*)ga,
                                       (__attribute__((address_space(3))) void*)&As[chunk * 512], 16, 0, 0);
      __builtin_amdgcn_global_load_lds((const __attribute__((address_space(1))) void*)gb,
                                       (__attribute__((address_space(3))) void*)&Bs[chunk * 512], 16, 0, 0);
    }
    __syncthreads();
    const int klo = (lane >> 4) * 8;
    bf16x8 af[4], bfr[4];
#pragma unroll
    for (int m = 0; m < 4; ++m)
      af[m] = *(const bf16x8*)&As[(wr * 64 + m * 16 + (lane & 15)) * 32 + klo];
#pragma unroll
    for (int n = 0; n < 4; ++n)
      bfr[n] = *(const bf16x8*)&Bs[(wc * 64 + n * 16 + (lane & 15)) * 32 + klo];
#pragma unroll
    for (int m = 0; m < 4; ++m)
#pragma unroll
      for (int n = 0; n < 4; ++n)
        acc[m][n] = __builtin_amdgcn_mfma_f32_16x16x32_bf16(af[m], bfr[n], acc[m][n], 0, 0, 0);
    __syncthreads();
  }
  const int cb = col0 + wc * 64 + (lane & 15);
  const int rb = row0 + wr * 64 + (lane >> 4) * 4;
#pragma unroll
  for (int m = 0; m < 4; ++m)
#pragma unroll
    for (int n = 0; n < 4; ++n)
#pragma unroll
      for (int j = 0; j < 4; ++j)
        C[(size_t)(rb + m * 16 + j) * 4096 + (cb + n * 16)] = f2b(acc[m][n][j]);
}

// ---------------------------------------------------------------- stage 2: attention
// grid 256 x 1, block 512 = 8 waves. wave = (half = w>>2, strip = w&3).
// LDS map: Kn0@0 (32K) Kn1@32K Kr0@64K (16K) Kr1@80K Vt@96K (32K). 128K total.
// 32x32x16 frag conventions: A row=lane&31,k=(lane>>5)*8+j; B col=lane&31,same k;
// C/D col=lane&31, row=(reg&3)+8*(reg>>2)+4*(lane>>5).
__global__ __launch_bounds__(512, 2)
void mla_attn_mfma(const float* __restrict__ q,
                   const u16* __restrict__ kvb,     // [T][16][256] bf16
                   const u16* __restrict__ ropeb,   // [T][64] bf16
                   float* __restrict__ out) {       // [T][16][128] fp32
  __shared__ __align__(16) unsigned char LB[131072];

  const int tid = threadIdx.x;
  const int w = tid >> 6, lane = tid & 63;
  const int l31 = lane & 31, hi = lane >> 5;
  const int half = w >> 2, strip = w & 3;

  const int bid = blockIdx.x;
  const int job = (bid & 7) * 32 + (bid >> 3);   // same-bh jobs -> same XCD
  const int bh = job >> 2, pr = job & 3;
  const int bat = bh >> 4, h = bh & 15;
  const int tok0 = bat * Sz;

  const int vkp = tid & 63, vdc = (tid >> 6) & 7;  // V stage: k-pair, d-chunk16

#pragma unroll 1
  for (int pass = 0; pass < 2; ++pass) {
    const int qt = pass ? pr : (7 - pr);
    const int ntiles = qt + 1;
    const int q0 = qt * 128 + strip * 32;         // wave's q-strip base (in-batch)

    // ---- Q fragments (B-operand), prescaled by SCALE
    bf16x8 qf[12];
    {
      const float* qp = q + ((size_t)(tok0 + q0 + l31) * Hz + h) * 192 + hi * 8;
#pragma unroll
      for (int ds = 0; ds < 12; ++ds) {
        float4 a = *(const float4*)(qp + ds * 16);
        float4 b = *(const float4*)(qp + ds * 16 + 4);
        union { bf16x8 v; u16 u[8]; } t;
        t.u[0] = f2b(a.x * SCALEf); t.u[1] = f2b(a.y * SCALEf);
        t.u[2] = f2b(a.z * SCALEf); t.u[3] = f2b(a.w * SCALEf);
        t.u[4] = f2b(b.x * SCALEf); t.u[5] = f2b(b.y * SCALEf);
        t.u[6] = f2b(b.z * SCALEf); t.u[7] = f2b(b.w * SCALEf);
        qf[ds] = t.v;
      }
    }

    f32x16 acc[4];
#pragma unroll
    for (int db = 0; db < 4; ++db)
#pragma unroll
      for (int r = 0; r < 16; ++r) acc[db][r] = 0.f;
    float m_run = -1e30f, l_run = 0.f;

    uint4 va0, va1, vb0, vb1;   // V prefetch (16 VGPR)

    // ---- prologue: stage tile 0
    {
      const int tokt = tok0;
#pragma unroll
      for (int i = 0; i < 4; ++i) {              // Kn: 32 chunks of 1KB
        const int c = w * 4 + i;
        const int row = c * 4 + (lane >> 4);
        const int sc = (lane & 15) ^ (row & 7);
        const u16* src = kvb + ((size_t)(tokt + row) * Hz + h) * 256 + sc * 8;
        __builtin_amdgcn_global_load_lds((const __attribute__((address_space(1))) void*)src,
                                         (__attribute__((address_space(3))) void*)(LB + c * 1024), 16, 0, 0);
      }
#pragma unroll
      for (int i = 0; i < 2; ++i) {              // Kr: 16 chunks of 1KB
        const int c = w * 2 + i;
        const int row = c * 8 + (lane >> 3);
        const int sc = (lane & 7) ^ (row & 7);
        const u16* src = ropeb + (size_t)(tokt + row) * 64 + sc * 8;
        __builtin_amdgcn_global_load_lds((const __attribute__((address_space(1))) void*)src,
                                         (__attribute__((address_space(3))) void*)(LB + 65536 + c * 1024), 16, 0, 0);
      }
      const u16* vp = kvb + ((size_t)(tokt + vkp * 2) * Hz + h) * 256 + 128 + vdc * 16;
      va0 = *(const uint4*)(vp);
      va1 = *(const uint4*)(vp + 8);
      vb0 = *(const uint4*)(vp + Hz * 256);
      vb1 = *(const uint4*)(vp + Hz * 256 + 8);
    }
    __syncthreads();
    { // write Vt(0): pack k-pairs, swizzle chunk ^= (d&7)
      union { uint4 v; u16 u[8]; } A0, A1, B0, B1;
      A0.v = va0; A1.v = va1; B0.v = vb0; B1.v = vb1;
      char* vt = (char*)(LB + 98304);
      const int inb = (4 * vkp) & 15, cc = vkp >> 2;
#pragma unroll
      for (int i = 0; i < 8; ++i) {
        { const int d = vdc * 16 + i;
          uint32_t wv = (uint32_t)A0.u[i] | ((uint32_t)B0.u[i] << 16);
          *(uint32_t*)(vt + d * 256 + 16 * (cc ^ (d & 7)) + inb) = wv; }
        { const int d = vdc * 16 + 8 + i;
          uint32_t wv = (uint32_t)A1.u[i] | ((uint32_t)B1.u[i] << 16);
          *(uint32_t*)(vt + d * 256 + 16 * (cc ^ (d & 7)) + inb) = wv; }
      }
    }
    __syncthreads();

#pragma unroll 1
    for (int t = 0; t < ntiles; ++t) {
      const int cur = t & 1;
      const bool havenext = (t + 1 < ntiles);
      if (havenext) {   // issue gll K(t+1) into buf cur^1 + V(t+1) regs
        const int tokt = tok0 + (t + 1) * 128;
#pragma unroll
        for (int i = 0; i < 4; ++i) {
          const int c = w * 4 + i;
          const int row = c * 4 + (lane >> 4);
          const int sc = (lane & 15) ^ (row & 7);
          const u16* src = kvb + ((size_t)(tokt + row) * Hz + h) * 256 + sc * 8;
          __builtin_amdgcn_global_load_lds((const __attribute__((address_space(1))) void*)src,
                                           (__attribute__((address_space(3))) void*)(LB + (cur ^ 1) * 32768 + c * 1024), 16, 0, 0);
        }
#pragma unroll
        for (int i = 0; i < 2; ++i) {
          const int c = w * 2 + i;
          const int row = c * 8 + (lane >> 3);
          const int sc = (lane & 7) ^ (row & 7);
          const u16* src = ropeb + (size_t)(tokt + row) * 64 + sc * 8;
          __builtin_amdgcn_global_load_lds((const __attribute__((address_space(1))) void*)src,
                                           (__attribute__((address_space(3))) void*)(LB + 65536 + (cur ^ 1) * 16384 + c * 1024), 16, 0, 0);
        }
        const u16* vp = kvb + ((size_t)(tokt + vkp * 2) * Hz + h) * 256 + 128 + vdc * 16;
        va0 = *(const uint4*)(vp);
        va1 = *(const uint4*)(vp + 8);
        vb0 = *(const uint4*)(vp + Hz * 256);
        vb1 = *(const uint4*)(vp + Hz * 256 + 8);
      }

      const bool active = (t * 128 + half * 64) <= (q0 + 31);
      if (active) {
        const u16* KnC = (const u16*)(LB + cur * 32768);
        const u16* KrC = (const u16*)(LB + 65536 + cur * 16384);
        // ---- swapped QK^T: S^T[64k x 32q], accumulate over d
        f32x16 s0, s1;
#pragma unroll
        for (int r = 0; r < 16; ++r) { s0[r] = 0.f; s1[r] = 0.f; }
        const int row_a = half * 64 + l31;        // kh=0 k-row
        const int row_b = row_a + 32;             // kh=1 k-row
#pragma unroll
        for (int ds = 0; ds < 8; ++ds) {
          bf16x8 k0v = *(const bf16x8*)&KnC[row_a * 128 + 8 * ((2 * ds + hi) ^ (row_a & 7))];
          bf16x8 k1v = *(const bf16x8*)&KnC[row_b * 128 + 8 * ((2 * ds + hi) ^ (row_b & 7))];
          s0 = __builtin_amdgcn_mfma_f32_32x32x16_bf16(k0v, qf[ds], s0, 0, 0, 0);
          s1 = __builtin_amdgcn_mfma_f32_32x32x16_bf16(k1v, qf[ds], s1, 0, 0, 0);
        }
#pragma unroll
        for (int ds = 8; ds < 12; ++ds) {
          bf16x8 k0v = *(const bf16x8*)&KrC[row_a * 64 + 8 * ((2 * (ds - 8) + hi) ^ (row_a & 7))];
          bf16x8 k1v = *(const bf16x8*)&KrC[row_b * 64 + 8 * ((2 * (ds - 8) + hi) ^ (row_b & 7))];
          s0 = __builtin_amdgcn_mfma_f32_32x32x16_bf16(k0v, qf[ds], s0, 0, 0, 0);
          s1 = __builtin_amdgcn_mfma_f32_32x32x16_bf16(k1v, qf[ds], s1, 0, 0, 0);
        }

        // ---- causal mask (diagonal tile only)
        if (t == qt) {
          const int qg = q0 + l31;
          const int kb0 = t * 128 + half * 64;
#pragma unroll
          for (int r = 0; r < 16; ++r) {
            const int cr_ = (r & 3) + 8 * (r >> 2) + 4 * hi;
            if (kb0 + cr_ > qg)      s0[r] = -1e30f;
            if (kb0 + 32 + cr_ > qg) s1[r] = -1e30f;
          }
        }

        // ---- in-register online softmax (lane owns q-column l31)
        float mx = -1e30f;
#pragma unroll
        for (int r = 0; r < 16; ++r) { mx = fmaxf(mx, s0[r]); mx = fmaxf(mx, s1[r]); }
        mx = fmaxf(mx, __shfl_xor(mx, 32));
        const bool need = __any(mx > m_run + 8.f);   // defer-max THR=8
        if (need) {
          const float nm = fmaxf(m_run, mx);
          const float cr = __expf(m_run - nm);
          m_run = nm; l_run *= cr;
#pragma unroll
          for (int r = 0; r < 16; ++r) {
            const float crg = __shfl(cr, (r & 3) + 8 * (r >> 2) + 4 * hi);
#pragma unroll
            for (int db = 0; db < 4; ++db) acc[db][r] *= crg;
          }
        }
        float ts = 0.f;
#pragma unroll
        for (int r = 0; r < 16; ++r) {
          s0[r] = __expf(s0[r] - m_run); ts += s0[r];
          s1[r] = __expf(s1[r] - m_run); ts += s1[r];
        }
        ts += __shfl_xor(ts, 32);
        l_run += ts;

        // ---- P -> A-frags: cvt_pk pairs + xor-32 word swap
        bf16x8 pf[4];
#pragma unroll
        for (int ks = 0; ks < 4; ++ks) {
          const int o = (ks & 1) * 8;
          uint32_t w0, w1, w2, w3;
          if (ks < 2) {
            w0 = cvtpk(s0[o + 0], s0[o + 1]); w1 = cvtpk(s0[o + 4], s0[o + 5]);
            w2 = cvtpk(s0[o + 2], s0[o + 3]); w3 = cvtpk(s0[o + 6], s0[o + 7]);
          } else {
            w0 = cvtpk(s1[o + 0], s1[o + 1]); w1 = cvtpk(s1[o + 4], s1[o + 5]);
            w2 = cvtpk(s1[o + 2], s1[o + 3]); w3 = cvtpk(s1[o + 6], s1[o + 7]);
          }
          const uint32_t t0 = __shfl_xor(w0, 32), t1 = __shfl_xor(w1, 32);
          const uint32_t t2 = __shfl_xor(w2, 32), t3 = __shfl_xor(w3, 32);
          union { bf16x8 v; uint32_t u[4]; } P;
          P.u[0] = hi ? t1 : w0;    // j=0,1
          P.u[1] = hi ? t3 : w2;    // j=2,3
          P.u[2] = hi ? w1 : t0;    // j=4,5
          P.u[3] = hi ? w3 : t2;    // j=6,7
          pf[ks] = P.v;
        }

        // ---- PV: O[32q x 128d] += P[32q x 64k] * V[64k x 128d]
        const u16* VtC = (const u16*)(LB + 98304);
#pragma unroll
        for (int ks = 0; ks < 4; ++ks)
#pragma unroll
          for (int db = 0; db < 4; ++db) {
            const int row = db * 32 + l31;
            bf16x8 vf = *(const bf16x8*)&VtC[row * 128 + 8 * ((half * 8 + 2 * ks + hi) ^ (row & 7))];
            acc[db] = __builtin_amdgcn_mfma_f32_32x32x16_bf16(pf[ks], vf, acc[db], 0, 0, 0);
          }
      }

      __syncthreads();   // A: all reads of Kn[cur]/Vt done; gll(t+1)+Vregs drained
      if (havenext) {
        union { uint4 v; u16 u[8]; } A0, A1, B0, B1;
        A0.v = va0; A1.v = va1; B0.v = vb0; B1.v = vb1;
        char* vt = (char*)(LB + 98304);
        const int inb = (4 * vkp) & 15, cc = vkp >> 2;
#pragma unroll
        for (int i = 0; i < 8; ++i) {
          { const int d = vdc * 16 + i;
            uint32_t wv = (uint32_t)A0.u[i] | ((uint32_t)B0.u[i] << 16);
            *(uint32_t*)(vt + d * 256 + 16 * (cc ^ (d & 7)) + inb) = wv; }
          { const int d = vdc * 16 + 8 + i;
            uint32_t wv = (uint32_t)A1.u[i] | ((uint32_t)B1.u[i] << 16);
            *(uint32_t*)(vt + d * 256 + 16 * (cc ^ (d & 7)) + inb) = wv; }
        }
        __syncthreads();  // B: Vt(t+1) published
      }
    }

    // ---- merge k-halves (waves w and w+4 share rows) + write out
    float* mb = (float*)LB;                 // 64KB acc buffer (Kn area, reads done)
    float* ml = (float*)(LB + 65536);       // m,l per strip
    if (half == 1) {
#pragma unroll
      for (int db = 0; db < 4; ++db)
#pragma unroll
        for (int q4 = 0; q4 < 4; ++q4) {
          float4 v = make_float4(acc[db][q4 * 4 + 0], acc[db][q4 * 4 + 1],
                                 acc[db][q4 * 4 + 2], acc[db][q4 * 4 + 3]);
          *(float4*)&mb[strip * 4096 + db * 1024 + q4 * 256 + lane * 4] = v;
        }
      if (lane < 32) { ml[strip * 64 + lane] = m_run; ml[strip * 64 + 32 + lane] = l_run; }
    }
    __syncthreads();
    if (half == 0) {
      const float mp = ml[strip * 64 + l31];
      const float lp = ml[strip * 64 + 32 + l31];
      const float M  = fmaxf(m_run, mp);
      const float sA = __expf(m_run - M);
      const float sB = __expf(mp - M);
      const float inv = 1.0f / (l_run * sA + lp * sB);
      const float fAl = sA * inv, fBl = sB * inv;
      float fA[16], fB[16];
#pragma unroll
      for (int r = 0; r < 16; ++r) {
        const int cr_ = (r & 3) + 8 * (r >> 2) + 4 * hi;
        fA[r] = __shfl(fAl, cr_);
        fB[r] = __shfl(fBl, cr_);
      }
#pragma unroll
      for (int db = 0; db < 4; ++db)
#pragma unroll
        for (int q4 = 0; q4 < 4; ++q4) {
          float4 pv = *(const float4*)&mb[strip * 4096 + db * 1024 + q4 * 256 + lane * 4];
#pragma unroll
          for (int jj = 0; jj < 4; ++jj) {
            const int r = q4 * 4 + jj;
            const int cr_ = (r & 3) + 8 * (r >> 2) + 4 * hi;
            const float pvj = (jj == 0) ? pv.x : (jj == 1) ? pv.y : (jj == 2) ? pv.z : pv.w;
            out[((size_t)(tok0 + q0 + cr_) * Hz + h) * 128 + db * 32 + l31] =
                acc[db][r] * fA[r] + pvj * fB[r];
          }
        }
    }
    __syncthreads();   // before next pass re-stages LDS
  }
}

// ---------------------------------------------------------------- launch
extern "C" void kernel_launch(void* const* d_in, const int* in_sizes, int n_in,
                              void* d_out, int out_size, void* d_ws, size_t ws_size,
                              hipStream_t stream) {
  const float* q    = (const float*)d_in[0];
  const float* ckv  = (const float*)d_in[1];
  const float* rope = (const float*)d_in[2];
  const float* wup  = (const float*)d_in[3];
  float* out = (float*)d_out;

  u16* ckvb  = (u16*)d_ws;
  u16* wupb  = ckvb + (size_t)4096 * RANKz;
  u16* kvb   = wupb + (size_t)4096 * RANKz;
  u16* ropeb = kvb + (size_t)4096 * 4096;

  const int nvec = 4096 * RANKz / 4;       // 524288 float4 per matrix
  const int nrope = 4096 * 64 / 4;         // 65536 float4
  cvt_bf16_kernel<<<(2 * nvec + nrope) / 256, 256, 0, stream>>>(ckv, ckvb, wup, wupb, rope, ropeb, nvec, nvec);

  dim3 gg(32, 32);
  gemm_kv_bf16<<<gg, 256, 0, stream>>>(ckvb, wupb, kvb);

  mla_attn_mfma<<<256, 512, 0, stream>>>(q, kvb, ropeb, out);
}